// Round 1
// baseline (3362.415 us; speedup 1.0000x reference)
//
#include <hip/hip_runtime.h>
#include <hip/hip_bf16.h>

// ---------------------------------------------------------------------------
// LocalizedPromptedAttentionLayer on MI355X (gfx950)
// B=32, N=576 patches, W=16 kv-window, d=768, P=4 prompts, H=12 heads, Dh=64
//
// Algebraic restructure:
//   q_x  = x @ (Wq@Wx)^T + (bq + Wq@bx)          [18432, 768]
//   qprm = prompt @ Wq^T + bq                     [4, 768]  (constant over B,N)
//   k    = y @ (Wk@Wy)^T + (bk + Wk@by)           never materialized (fused)
//   v    = y @ (Wv@Wy)^T + (bv + Wv@by)           never materialized (fused)
//   o    = softmax(q k^T / 8) v                   [92160, 768] f32 in ws
//   out  = o @ out_w^T + out_b                    [92160, 768] f32 -> d_out
// ---------------------------------------------------------------------------

typedef __attribute__((ext_vector_type(8))) short bf16x8;   // MFMA A/B frag
typedef __attribute__((ext_vector_type(4))) float f32x4;    // MFMA C/D frag
typedef __attribute__((ext_vector_type(4))) unsigned short u16x4;
typedef __attribute__((ext_vector_type(8))) unsigned short u16x8;

__device__ __forceinline__ float bf2f(unsigned short u) {
  union { unsigned int i; float f; } x; x.i = ((unsigned int)u) << 16; return x.f;
}
__device__ __forceinline__ unsigned short f2b(float f) {
  union { float f; unsigned int i; } x; x.f = f;
  unsigned int u = x.i;
  return (unsigned short)((u + 0x7fffu + ((u >> 16) & 1u)) >> 16);  // RNE
}

// ---------------- f32 -> bf16 bulk convert (out_w) ----------------
__global__ void k_f2b(const float* __restrict__ src, unsigned short* __restrict__ dst, int n4) {
  int stride = gridDim.x * blockDim.x;
  for (int i = blockIdx.x * blockDim.x + threadIdx.x; i < n4; i += stride) {
    float4 v = ((const float4*)src)[i];
    u16x4 o = { f2b(v.x), f2b(v.y), f2b(v.z), f2b(v.w) };
    ((u16x4*)dst)[i] = o;
  }
}

// ---------------- weight fusion: C[j,i] = sum_k A[j,k] * B[k,i] (bf16 out) ----------------
__global__ __launch_bounds__(256) void k_wfuse(const float* __restrict__ A,
                                               const float* __restrict__ Bm,
                                               unsigned short* __restrict__ C,
                                               int K, int lda, int ncols) {
  int i  = blockIdx.x * 256 + threadIdx.x;
  int j0 = blockIdx.y * 8;
  float acc[8] = {0.f,0.f,0.f,0.f,0.f,0.f,0.f,0.f};
  for (int k = 0; k < K; ++k) {
    float wb = Bm[(long)k * ncols + i];
#pragma unroll
    for (int r = 0; r < 8; ++r) acc[r] += A[(long)(j0 + r) * lda + k] * wb;
  }
#pragma unroll
  for (int r = 0; r < 8; ++r) C[(long)(j0 + r) * ncols + i] = f2b(acc[r]);
}

// ---------------- fused biases: bqx = bq + Wq@bx ; bkv = [bk + Wk@by ; bv + Wv@by] ----------------
__global__ void k_bfuse(const float* __restrict__ ipw, const float* __restrict__ ipb,
                        const float* __restrict__ bx, const float* __restrict__ by,
                        float* __restrict__ bqx, float* __restrict__ bkv) {
  int o    = blockIdx.x * 4 + (threadIdx.x >> 6);   // 0..2303 (grid 576)
  int lane = threadIdx.x & 63;
  int sec  = o / 768, jj = o - sec * 768;
  const float* Arow = ipw + (long)o * 768;
  const float* vb   = (sec == 0) ? bx : by;
  float s = 0.f;
  for (int k = lane; k < 768; k += 64) s += Arow[k] * vb[k];
#pragma unroll
  for (int d = 32; d > 0; d >>= 1) s += __shfl_down(s, d);
  if (lane == 0) {
    s += ipb[o];
    if (sec == 0) bqx[jj] = s;
    else if (sec == 1) bkv[jj] = s;
    else bkv[768 + jj] = s;
  }
}

// ---------------- prompt queries: qp[p,j] = prompt[p]·Wq[j] + bq[j] (bf16) ----------------
__global__ void k_qprompt(const float* __restrict__ ipw, const float* __restrict__ ipb,
                          const float* __restrict__ prompt, unsigned short* __restrict__ qpf) {
  int o    = blockIdx.x * 4 + (threadIdx.x >> 6);   // 0..3071 (grid 768)
  int lane = threadIdx.x & 63;
  int p = o / 768, j = o - p * 768;
  const float* Wqr = ipw + (long)j * 768;
  const float* pr  = prompt + (long)p * 768;
  float s = 0.f;
  for (int k = lane; k < 768; k += 64) s += Wqr[k] * pr[k];
#pragma unroll
  for (int d = 32; d > 0; d >>= 1) s += __shfl_down(s, d);
  if (lane == 0) qpf[o] = f2b(s + ipb[j]);
}

// ---------------- generic GEMM: C[M,N] = A_f32[M,K] @ Bw_bf16[N,K]^T + bias ----------------
// 256 thr = 4 waves (2x2), tile 128x128, BK=32, double-buffered LDS, bf16 MFMA.
template <typename OutT>
__global__ __launch_bounds__(256) void k_gemm_bt(const float* __restrict__ A,
                                                 const unsigned short* __restrict__ Bw,
                                                 const float* __restrict__ bias,
                                                 OutT* __restrict__ C,
                                                 int M, int Nn, int K) {
  const int tid  = threadIdx.x;
  const int lane = tid & 63, wid = tid >> 6;
  const int wm = wid >> 1, wn = wid & 1;
  const int lr = lane & 15, lk = lane >> 4;
  const int m0 = blockIdx.y * 128, n0 = blockIdx.x * 128;

  __shared__ unsigned short As[2][128 * 32];
  __shared__ unsigned short Bs[2][128 * 32];

  f32x4 acc[4][4];
#pragma unroll
  for (int nt = 0; nt < 4; ++nt) {
    float bv = bias[n0 + wn * 64 + nt * 16 + lr];
    f32x4 bvv = {bv, bv, bv, bv};
#pragma unroll
    for (int mt = 0; mt < 4; ++mt) acc[mt][nt] = bvv;
  }

  const int NS = K >> 5;
  u16x8 pa[2], pb[2];

  auto ldA = [&](int ks, u16x8* p) {
#pragma unroll
    for (int s = 0; s < 2; ++s) {
      int c = tid + s * 256, row = c >> 2, k8 = (c & 3) * 8;
      const float* src = &A[(long)(m0 + row) * K + ks * 32 + k8];
      float4 v0 = *(const float4*)src, v1 = *(const float4*)(src + 4);
      u16x8 t = { f2b(v0.x), f2b(v0.y), f2b(v0.z), f2b(v0.w),
                  f2b(v1.x), f2b(v1.y), f2b(v1.z), f2b(v1.w) };
      p[s] = t;
    }
  };
  auto ldB = [&](int ks, u16x8* p) {
#pragma unroll
    for (int s = 0; s < 2; ++s) {
      int c = tid + s * 256, row = c >> 2, k8 = (c & 3) * 8;
      p[s] = *(const u16x8*)&Bw[(long)(n0 + row) * K + ks * 32 + k8];
    }
  };
  auto stS = [&](int buf) {
#pragma unroll
    for (int s = 0; s < 2; ++s) {
      int c = tid + s * 256, row = c >> 2, k8 = (c & 3) * 8;
      *(u16x8*)&As[buf][row * 32 + k8] = pa[s];
      *(u16x8*)&Bs[buf][row * 32 + k8] = pb[s];
    }
  };

  ldA(0, pa); ldB(0, pb);
  stS(0);
  ldA(1, pa); ldB(1, pb);
  __syncthreads();

  for (int ks = 0; ks < NS; ++ks) {
    if (ks + 1 < NS) stS((ks + 1) & 1);
    if (ks + 2 < NS) { ldA(ks + 2, pa); ldB(ks + 2, pb); }
    const int cur = ks & 1;
    bf16x8 af[4], bfr[4];
#pragma unroll
    for (int mt = 0; mt < 4; ++mt)
      af[mt] = *(const bf16x8*)&As[cur][(wm * 64 + mt * 16 + lr) * 32 + lk * 8];
#pragma unroll
    for (int nt = 0; nt < 4; ++nt)
      bfr[nt] = *(const bf16x8*)&Bs[cur][(wn * 64 + nt * 16 + lr) * 32 + lk * 8];
#pragma unroll
    for (int mt = 0; mt < 4; ++mt)
#pragma unroll
      for (int nt = 0; nt < 4; ++nt)
        acc[mt][nt] = __builtin_amdgcn_mfma_f32_16x16x32_bf16(af[mt], bfr[nt], acc[mt][nt], 0, 0, 0);
    __syncthreads();
  }

#pragma unroll
  for (int mt = 0; mt < 4; ++mt)
#pragma unroll
    for (int nt = 0; nt < 4; ++nt) {
      int col = n0 + wn * 64 + nt * 16 + lr;
#pragma unroll
      for (int r = 0; r < 4; ++r) {
        int row = m0 + wm * 64 + mt * 16 + lk * 4 + r;
        float v = acc[mt][nt][r];
        if constexpr (sizeof(OutT) == 4) C[(long)row * Nn + col] = v;
        else                             C[(long)row * Nn + col] = f2b(v);
      }
    }
}

// ---------------- fused k/v GEMM + attention ----------------
// 1 block = 8 consecutive patches (128 y rows). 512 thr = 8 waves (2Mx4N).
// Per head-group (2 heads): k,v = y[128,1024] @ Wkv_slice^T -> LDS [128,128]x2,
// then scores/softmax/PV on VALU, o written f32 to obuf.
__global__ __launch_bounds__(512) void k_kv_attn(const float* __restrict__ y,
                                                 const unsigned short* __restrict__ Wkv,
                                                 const float* __restrict__ bkv,
                                                 const unsigned short* __restrict__ qx,
                                                 const unsigned short* __restrict__ qp,
                                                 float* __restrict__ obuf) {
  const int tid  = threadIdx.x;
  const int lane = tid & 63, wid = tid >> 6;
  const int wm = wid >> 2, wn = wid & 3;
  const int lr = lane & 15, lk = lane >> 4;
  const int bidx = blockIdx.x;
  const int b = bidx / 72, n0 = (bidx - b * 72) * 8;

  const float* __restrict__ yb = y + ((long)b * 9216 + (long)n0 * 16) * 1024;

  __shared__ unsigned short Ys[2][128 * 32];  // y tile bf16
  __shared__ unsigned short Ws[2][256 * 32];  // W_kv tile (128 k-rows + 128 v-rows)
  __shared__ unsigned short Ks[128 * 128];
  __shared__ unsigned short Vs[128 * 128];
  __shared__ unsigned short Qs[40 * 128];     // 8 patches x 5 q x 128 feat
  __shared__ float          Ss[80 * 16];      // scores

  for (int hg = 0; hg < 6; ++hg) {
    // acc init with fused k/v bias
    f32x4 acc[4][4];
#pragma unroll
    for (int nt = 0; nt < 4; ++nt) {
      int col = wn * 64 + nt * 16 + lr;  // 0..255: <128 => k, >=128 => v
      float bv = (col < 128) ? bkv[hg * 128 + col] : bkv[768 + hg * 128 + (col - 128)];
      f32x4 bvv = {bv, bv, bv, bv};
#pragma unroll
      for (int mt = 0; mt < 4; ++mt) acc[mt][nt] = bvv;
    }

    u16x4 py[2]; u16x8 pw[2];
    auto ldY = [&](int ks) {
#pragma unroll
      for (int s = 0; s < 2; ++s) {
        int c = tid + s * 512, row = c >> 3, f4 = c & 7;
        float4 v = *(const float4*)&yb[(long)row * 1024 + ks * 32 + f4 * 4];
        u16x4 t = { f2b(v.x), f2b(v.y), f2b(v.z), f2b(v.w) };
        py[s] = t;
      }
    };
    auto ldW = [&](int ks) {
#pragma unroll
      for (int s = 0; s < 2; ++s) {
        int c = tid + s * 512, wr = c >> 2, k8 = (c & 3) * 8;
        int wrow = hg * 128 + wr + ((wr >= 128) ? 640 : 0);  // v rows offset by 768-128
        pw[s] = *(const u16x8*)&Wkv[(long)wrow * 1024 + ks * 32 + k8];
      }
    };
    auto stS = [&](int buf) {
#pragma unroll
      for (int s = 0; s < 2; ++s) {
        int c = tid + s * 512;
        int row = c >> 3, f4 = c & 7;
        *(u16x4*)&Ys[buf][row * 32 + f4 * 4] = py[s];
        int wr = c >> 2, k8 = (c & 3) * 8;
        *(u16x8*)&Ws[buf][wr * 32 + k8] = pw[s];
      }
    };

    ldY(0); ldW(0);
    stS(0);
    ldY(1); ldW(1);
    __syncthreads();

    for (int ks = 0; ks < 32; ++ks) {
      if (ks + 1 < 32) stS((ks + 1) & 1);
      if (ks + 2 < 32) { ldY(ks + 2); ldW(ks + 2); }
      const int cur = ks & 1;
      bf16x8 af[4], bfr[4];
#pragma unroll
      for (int mt = 0; mt < 4; ++mt)
        af[mt] = *(const bf16x8*)&Ys[cur][(wm * 64 + mt * 16 + lr) * 32 + lk * 8];
#pragma unroll
      for (int nt = 0; nt < 4; ++nt)
        bfr[nt] = *(const bf16x8*)&Ws[cur][(wn * 64 + nt * 16 + lr) * 32 + lk * 8];
#pragma unroll
      for (int mt = 0; mt < 4; ++mt)
#pragma unroll
        for (int nt = 0; nt < 4; ++nt)
          acc[mt][nt] = __builtin_amdgcn_mfma_f32_16x16x32_bf16(af[mt], bfr[nt], acc[mt][nt], 0, 0, 0);
      __syncthreads();
    }

    // write k,v (bf16) into LDS
#pragma unroll
    for (int mt = 0; mt < 4; ++mt)
#pragma unroll
      for (int nt = 0; nt < 4; ++nt) {
        int colw = wn * 64 + nt * 16 + lr;
#pragma unroll
        for (int r = 0; r < 4; ++r) {
          int row = wm * 64 + mt * 16 + lk * 4 + r;
          unsigned short hv = f2b(acc[mt][nt][r]);
          if (colw < 128) Ks[row * 128 + colw]         = hv;
          else            Vs[row * 128 + (colw - 128)] = hv;
        }
      }

    // load q slice (8 patches x [x-row + 4 prompt rows] x 128 feats)
    for (int c = tid; c < 640; c += 512) {
      int qrow = c >> 4, cc = c & 15;
      int p = qrow / 5, q5 = qrow - p * 5;
      const unsigned short* src = (q5 == 0)
          ? &qx[((long)(b * 576 + n0 + p)) * 768 + hg * 128 + cc * 8]
          : &qp[((long)(q5 - 1)) * 768 + hg * 128 + cc * 8];
      *(u16x8*)&Qs[qrow * 128 + cc * 8] = *(const u16x8*)src;
    }
    __syncthreads();

    // scores = q k^T / 8
    for (int idx = tid; idx < 1280; idx += 512) {
      int w16 = idx & 15, rest = idx >> 4;
      int q5 = rest % 5, ph = rest / 5;
      int p = ph >> 1, h = ph & 1;
      const u16x8* qv = (const u16x8*)&Qs[(p * 5 + q5) * 128 + h * 64];
      const u16x8* kv = (const u16x8*)&Ks[(p * 16 + w16) * 128 + h * 64];
      float s = 0.f;
#pragma unroll
      for (int j = 0; j < 8; ++j) {
        u16x8 qq = qv[j], kk = kv[j];
#pragma unroll
        for (int e = 0; e < 8; ++e) s += bf2f(qq[e]) * bf2f(kk[e]);
      }
      Ss[rest * 16 + w16] = s * 0.125f;
    }
    __syncthreads();

    // softmax over 16
    if (tid < 80) {
      float* row = &Ss[tid * 16];
      float m = row[0];
#pragma unroll
      for (int j = 1; j < 16; ++j) m = fmaxf(m, row[j]);
      float sum = 0.f;
#pragma unroll
      for (int j = 0; j < 16; ++j) { float e = __expf(row[j] - m); row[j] = e; sum += e; }
      float inv = 1.f / sum;
#pragma unroll
      for (int j = 0; j < 16; ++j) row[j] *= inv;
    }
    __syncthreads();

    // o = attn @ v  -> obuf (f32)
    for (int idx = tid; idx < 5120; idx += 512) {
      int dh = idx & 63, r = idx >> 6;
      int q5 = r % 5, ph = r / 5;
      int p = ph >> 1, h = ph & 1;
      const float* arow = &Ss[r * 16];
      const unsigned short* vcol = &Vs[p * 16 * 128 + h * 64 + dh];
      float o = 0.f;
#pragma unroll
      for (int w = 0; w < 16; ++w) o += arow[w] * bf2f(vcol[w * 128]);
      long orow = ((long)(b * 576 + n0 + p)) * 5 + q5;
      obuf[orow * 768 + (hg * 2 + h) * 64 + dh] = o;
    }
    __syncthreads();
  }
}

// ---------------------------------------------------------------------------
extern "C" void kernel_launch(void* const* d_in, const int* in_sizes, int n_in,
                              void* d_out, int out_size, void* d_ws, size_t ws_size,
                              hipStream_t stream) {
  const float* x      = (const float*)d_in[0];   // [32,576,1536]
  const float* y      = (const float*)d_in[1];   // [32,9216,1024]
  const float* Wx     = (const float*)d_in[2];   // [768,1536]
  const float* bx     = (const float*)d_in[3];   // [768]
  const float* Wy     = (const float*)d_in[4];   // [768,1024]
  const float* by     = (const float*)d_in[5];   // [768]
  const float* prompt = (const float*)d_in[6];   // [1,4,768]
  const float* ipw    = (const float*)d_in[7];   // [2304,768]
  const float* ipb    = (const float*)d_in[8];   // [2304]
  const float* outw   = (const float*)d_in[9];   // [768,768]
  const float* outb   = (const float*)d_in[10];  // [768]
  float* out = (float*)d_out;

  char* ws = (char*)d_ws;
  size_t off = 0;
  auto alloc = [&](size_t bytes) -> void* {
    void* p = ws + off; off += (bytes + 255) & ~(size_t)255; return p;
  };
  unsigned short* qxb  = (unsigned short*)alloc(18432UL * 768 * 2);   // q_x bf16
  unsigned short* Wqx  = (unsigned short*)alloc(768UL * 1536 * 2);
  unsigned short* Wkv  = (unsigned short*)alloc(1536UL * 1024 * 2);
  unsigned short* oww  = (unsigned short*)alloc(768UL * 768 * 2);
  unsigned short* qpf  = (unsigned short*)alloc(4UL * 768 * 2);
  float*          bqx  = (float*)alloc(768 * 4);
  float*          bkv  = (float*)alloc(1536 * 4);
  float*          obuf = (float*)alloc(92160UL * 768 * 4);            // o f32

  // weight prep
  k_f2b<<<dim3(256), dim3(256), 0, stream>>>(outw, oww, 768 * 768 / 4);
  k_wfuse<<<dim3(6, 96), dim3(256), 0, stream>>>(ipw,              Wx, Wqx,              768, 768, 1536);
  k_wfuse<<<dim3(4, 96), dim3(256), 0, stream>>>(ipw + 768 * 768,  Wy, Wkv,              768, 768, 1024);
  k_wfuse<<<dim3(4, 96), dim3(256), 0, stream>>>(ipw + 1536 * 768, Wy, Wkv + 768 * 1024, 768, 768, 1024);
  k_bfuse<<<dim3(576), dim3(256), 0, stream>>>(ipw, ipb, bx, by, bqx, bkv);
  k_qprompt<<<dim3(768), dim3(256), 0, stream>>>(ipw, ipb, prompt, qpf);

  // q_x = x @ Wqx^T + bqx   (M=18432, N=768, K=1536) -> bf16
  k_gemm_bt<unsigned short><<<dim3(6, 144), dim3(256), 0, stream>>>(
      x, Wqx, bqx, qxb, 18432, 768, 1536);

  // fused k/v + attention -> obuf
  k_kv_attn<<<dim3(2304), dim3(512), 0, stream>>>(y, Wkv, bkv, qxb, qpf, obuf);

  // out = o @ out_w^T + out_b   (M=92160, N=768, K=768) -> f32
  k_gemm_bt<float><<<dim3(6, 720), dim3(256), 0, stream>>>(
      obuf, oww, outb, out, 92160, 768, 768);
}